// Round 1
// baseline (325.872 us; speedup 1.0000x reference)
//
#include <hip/hip_runtime.h>

using f32x4 = __attribute__((ext_vector_type(4))) float;
using s16x8 = __attribute__((ext_vector_type(8))) short;
using u16x4 = __attribute__((ext_vector_type(4))) ushort;

constexpr int NB   = 16;    // batch
constexpr int CH   = 256;   // channels
constexpr int TT   = 4096;  // time
constexpr int NT   = 64;    // tokens per tile
constexpr int HALO = 8;     // (K-1)*DIL
constexpr int XROWS = NT + HALO;  // 72
constexpr int ROWB  = 512;        // bytes per LDS row: 256 ch * 2B, no pad (swizzled)

__device__ __forceinline__ ushort f2b(float f) {
    unsigned u; __builtin_memcpy(&u, &f, 4);
    u += 0x7FFFu + ((u >> 16) & 1u);   // RNE
    return (ushort)(u >> 16);
}
__device__ __forceinline__ float fast_sigmoid(float x) {
    return __builtin_amdgcn_rcpf(1.f + __expf(-x));
}
__device__ __forceinline__ float fast_tanh(float x) {
    return 2.f * __builtin_amdgcn_rcpf(1.f + __expf(-2.f * x)) - 1.f;
}
// XOR swizzle: row stride 512B == 0 (mod 128B), spread rows across the 8
// 16B slots of the bank array. Keeps 16B alignment (only bits 4..6 flip).
__device__ __forceinline__ int swz(int row, int colB) {
    return row * ROWB + (colB ^ ((row & 7) << 4));
}

// Weight prep: f32 -> bf16.
// W1[m][k]: m<256 filter / m>=256 gate, k = tap*256 + in_ch.
// W2[m][i]: m<256 res / m>=256 skip.
__global__ __launch_bounds__(512)
void prep_w(const float* __restrict__ wf, const float* __restrict__ wg,
            const float* __restrict__ wr, const float* __restrict__ wsk,
            ushort* __restrict__ W1, ushort* __restrict__ W2) {
    int g = blockIdx.x * 512 + threadIdx.x;
    if (g < 512 * 64) {                       // W1: 512 rows x 64 threads (4 i each)
        int m = g >> 6, i0 = (g & 63) * 4;
        const float* src = (m < 256) ? wf + ((size_t)m << 9)
                                     : wg + ((size_t)(m - 256) << 9);
        // src row layout: idx = i*2 + tap
        f32x4 a = *(const f32x4*)&src[i0 * 2];
        f32x4 c = *(const f32x4*)&src[i0 * 2 + 4];
        u16x4 t0v = { f2b(a[0]), f2b(a[2]), f2b(c[0]), f2b(c[2]) };
        u16x4 t1v = { f2b(a[1]), f2b(a[3]), f2b(c[1]), f2b(c[3]) };
        *(u16x4*)&W1[(size_t)m * 512 + i0]       = t0v;   // tap 0 block
        *(u16x4*)&W1[(size_t)m * 512 + 256 + i0] = t1v;   // tap 1 block
    } else {                                  // W2: 512 rows x 64 threads
        int g2 = g - 512 * 64;
        int m = g2 >> 6, i0 = (g2 & 63) * 4;
        const float* src = (m < 256) ? wr + ((size_t)m << 8)
                                     : wsk + ((size_t)(m - 256) << 8);
        f32x4 a = *(const f32x4*)&src[i0];
        u16x4 o = { f2b(a[0]), f2b(a[1]), f2b(a[2]), f2b(a[3]) };
        *(u16x4*)&W2[(size_t)m * 256 + i0] = o;
    }
}

// 512 threads = 8 waves. Wave w owns output channels [w*32, w*32+32).
// MFMA roles: A = x-fragment (M = 16 tokens, row = lane&15),
//             B = W-fragment (N = 16 out-channels, col = lane&15).
// => D: row = quad*4+r = token, col = lane&15 = channel
// => each lane holds 4 CONSECUTIVE TOKENS of one channel -> f32x4 epilogue.
__global__ __launch_bounds__(512, 4)
void fused_block(const float* __restrict__ x,
                 const ushort* __restrict__ W1, const ushort* __restrict__ W2,
                 const float* __restrict__ b_filt, const float* __restrict__ b_gate,
                 const float* __restrict__ b_res,  const float* __restrict__ b_skip,
                 float* __restrict__ out) {
    // rows 0..71: x[token][channel] bf16 swizzled (token = t0-8+row);
    // after GEMM1, rows 0..63 are reused for z[token][channel].
    __shared__ __align__(16) char lds[XROWS * ROWB];   // 36864 B

    const int tid = threadIdx.x;
    const int b  = blockIdx.x >> 6;
    const int t0 = (blockIdx.x & 63) * NT;
    const float* X = x + (size_t)b * CH * TT;
    const int tg0 = t0 - HALO;

    // ---------------- stage x (f32 -> bf16, transposed, swizzled) ----------------
    {
        const int tc4 = tid & 3;          // token sub-chunk (4 tokens)
        const int cp  = tid >> 2;         // channel pair 0..127
        const int c0  = cp * 2;
        const float* Xa = X + (size_t)c0 * TT;
        const float* Xb = Xa + TT;
        #pragma unroll
        for (int it = 0; it < 4; ++it) {  // rows 0..63
            int tg = tg0 + it * 16 + tc4 * 4;
            f32x4 va = (f32x4){0.f,0.f,0.f,0.f}, vb = va;
            if (tg >= 0) { va = *(const f32x4*)&Xa[tg]; vb = *(const f32x4*)&Xb[tg]; }
            #pragma unroll
            for (int e = 0; e < 4; ++e) {
                int row = it * 16 + tc4 * 4 + e;
                unsigned pk = (unsigned)f2b(va[e]) | ((unsigned)f2b(vb[e]) << 16);
                *(unsigned*)(lds + swz(row, cp * 4)) = pk;
            }
        }
        // tail rows 64..71 = tokens t0+56..t0+63 (always in range)
        int c = tid & 255, half = tid >> 8;
        f32x4 v = *(const f32x4*)&X[(size_t)c * TT + tg0 + 64 + half * 4];
        #pragma unroll
        for (int e = 0; e < 4; ++e) {
            int row = 64 + half * 4 + e;
            *(ushort*)(lds + swz(row, c * 2)) = f2b(v[e]);
        }
    }
    __syncthreads();

    const int wv = tid >> 6, lane = tid & 63;
    const int l16 = lane & 15, quad = lane >> 4;
    // B-operand row bases: cn 0/1 = filter ch, cn 2/3 = gate ch (paired with 0/1)
    int mrow[4];
    mrow[0] = wv * 32 + l16;        mrow[1] = wv * 32 + 16 + l16;
    mrow[2] = 256 + mrow[0];        mrow[3] = 256 + mrow[1];

    // ---------------- GEMM1: acc[token-tile][ch-tile] over K=512 ----------------
    f32x4 acc[4][4];
    #pragma unroll
    for (int i = 0; i < 4; ++i)
        #pragma unroll
        for (int j = 0; j < 4; ++j) acc[i][j] = (f32x4){0.f,0.f,0.f,0.f};

    #pragma unroll
    for (int kq = 0; kq < 16; ++kq) {
        const int tap = kq >> 3, ci = kq & 7;
        s16x8 xf[4];
        #pragma unroll
        for (int tm = 0; tm < 4; ++tm) {
            int row = tm * 16 + l16 + 8 * tap;
            xf[tm] = *(const s16x8*)(lds + swz(row, ci * 64 + quad * 16));
        }
        #pragma unroll
        for (int cn = 0; cn < 4; ++cn) {
            s16x8 wfr = *(const s16x8*)&W1[(size_t)mrow[cn] * 512 + kq * 32 + quad * 8];
            #pragma unroll
            for (int tm = 0; tm < 4; ++tm)
                acc[tm][cn] = __builtin_amdgcn_mfma_f32_16x16x32_bf16(xf[tm], wfr, acc[tm][cn], 0, 0, 0);
        }
    }
    __syncthreads();   // all GEMM1 LDS reads done before z overwrites rows 0..63

    // ---------------- activations -> z (bf16) rows 0..63 ----------------
    #pragma unroll
    for (int cn = 0; cn < 2; ++cn) {
        const int zc = wv * 32 + cn * 16 + l16;
        const float bfv = b_filt[zc], bgv = b_gate[zc];
        #pragma unroll
        for (int tm = 0; tm < 4; ++tm) {
            #pragma unroll
            for (int r = 0; r < 4; ++r) {
                float fv = acc[tm][cn][r]     + bfv;
                float gv = acc[tm][cn + 2][r] + bgv;
                int row = tm * 16 + quad * 4 + r;
                *(ushort*)(lds + swz(row, zc * 2)) = f2b(fast_tanh(fv) * fast_sigmoid(gv));
            }
        }
    }
    __syncthreads();

    // ---------------- GEMM2: acc2[token-tile][ch-tile] over K=256 ----------------
    f32x4 acc2[4][4];
    #pragma unroll
    for (int i = 0; i < 4; ++i)
        #pragma unroll
        for (int j = 0; j < 4; ++j) acc2[i][j] = (f32x4){0.f,0.f,0.f,0.f};

    #pragma unroll
    for (int kq = 0; kq < 8; ++kq) {
        s16x8 zf[4];
        #pragma unroll
        for (int tm = 0; tm < 4; ++tm) {
            int row = tm * 16 + l16;
            zf[tm] = *(const s16x8*)(lds + swz(row, kq * 64 + quad * 16));
        }
        #pragma unroll
        for (int cn = 0; cn < 4; ++cn) {
            s16x8 wfr = *(const s16x8*)&W2[(size_t)mrow[cn] * 256 + kq * 32 + quad * 8];
            #pragma unroll
            for (int tm = 0; tm < 4; ++tm)
                acc2[tm][cn] = __builtin_amdgcn_mfma_f32_16x16x32_bf16(zf[tm], wfr, acc2[tm][cn], 0, 0, 0);
        }
    }

    // ---------------- epilogue: vectorized f32x4 stores ----------------
    const size_t OUT1 = (size_t)NB * CH * TT;
    #pragma unroll
    for (int cn = 0; cn < 2; ++cn) {
        const int ch = wv * 32 + cn * 16 + l16;
        const float br = b_res[ch], bs = b_skip[ch];
        const float* Xc = X + (size_t)ch * TT + t0;
        float* O0 = out + ((size_t)(b * CH + ch)) * TT + t0;
        float* O1 = O0 + OUT1;
        #pragma unroll
        for (int tm = 0; tm < 4; ++tm) {
            const int ttk = tm * 16 + quad * 4;
            f32x4 xv = *(const f32x4*)&Xc[ttk];       // exact f32 x (L2-hot)
            f32x4 o0, o1;
            #pragma unroll
            for (int r = 0; r < 4; ++r) {
                o0[r] = xv[r] + acc2[tm][cn][r] + br;
                o1[r] = acc2[tm][cn + 2][r] + bs;
            }
            *(f32x4*)&O0[ttk] = o0;
            *(f32x4*)&O1[ttk] = o1;
        }
    }
}

extern "C" void kernel_launch(void* const* d_in, const int* in_sizes, int n_in,
                              void* d_out, int out_size, void* d_ws, size_t ws_size,
                              hipStream_t stream) {
    const float* x   = (const float*)d_in[0];
    const float* wf  = (const float*)d_in[1];
    const float* bfi = (const float*)d_in[2];
    const float* wg  = (const float*)d_in[3];
    const float* bg  = (const float*)d_in[4];
    const float* wr  = (const float*)d_in[5];
    const float* br  = (const float*)d_in[6];
    const float* wsk = (const float*)d_in[7];
    const float* bs  = (const float*)d_in[8];

    ushort* W1 = (ushort*)d_ws;                  // 512*512 bf16
    ushort* W2 = W1 + 512 * 512;                 // 512*256 bf16

    prep_w<<<128, 512, 0, stream>>>(wf, wg, wr, wsk, W1, W2);

    const int nBlocks = NB * (TT / NT);          // 1024
    fused_block<<<nBlocks, 512, 0, stream>>>(x, W1, W2, bfi, bg, br, bs,
                                             (float*)d_out);
}

// Round 2
// 270.065 us; speedup vs baseline: 1.2066x; 1.2066x over previous
//
#include <hip/hip_runtime.h>

using f32x4 = __attribute__((ext_vector_type(4))) float;
using s16x8 = __attribute__((ext_vector_type(8))) short;
using u16x4 = __attribute__((ext_vector_type(4))) ushort;

constexpr int NB   = 16;    // batch
constexpr int CH   = 256;   // channels
constexpr int TT   = 4096;  // time
constexpr int NT   = 128;   // tokens per tile
constexpr int HALO = 8;     // (K-1)*DIL
constexpr int XROWS = NT + HALO;  // 136
constexpr int ROWB  = 512;        // bytes per LDS row: 256 ch * 2B, swizzled

__device__ __forceinline__ ushort f2b(float f) {
    unsigned u; __builtin_memcpy(&u, &f, 4);
    u += 0x7FFFu + ((u >> 16) & 1u);   // RNE
    return (ushort)(u >> 16);
}
__device__ __forceinline__ float fast_sigmoid(float x) {
    return __builtin_amdgcn_rcpf(1.f + __expf(-x));
}
__device__ __forceinline__ float fast_tanh(float x) {
    return 2.f * __builtin_amdgcn_rcpf(1.f + __expf(-2.f * x)) - 1.f;
}
// XOR swizzle: row stride 512B == 0 (mod 128B); spread rows across the 8
// 16B slots of the bank array. Keeps 16B alignment (only bits 4..6 flip).
__device__ __forceinline__ int swz(int row, int colB) {
    return row * ROWB + (colB ^ ((row & 7) << 4));
}

// Weight prep: f32 -> bf16.
// W1[m][k]: m<256 filter / m>=256 gate, k = tap*256 + in_ch.
// W2[m][i]: m<256 res / m>=256 skip.
__global__ __launch_bounds__(512)
void prep_w(const float* __restrict__ wf, const float* __restrict__ wg,
            const float* __restrict__ wr, const float* __restrict__ wsk,
            ushort* __restrict__ W1, ushort* __restrict__ W2) {
    int g = blockIdx.x * 512 + threadIdx.x;
    if (g < 512 * 64) {                       // W1: 512 rows x 64 threads (4 i each)
        int m = g >> 6, i0 = (g & 63) * 4;
        const float* src = (m < 256) ? wf + ((size_t)m << 9)
                                     : wg + ((size_t)(m - 256) << 9);
        f32x4 a = *(const f32x4*)&src[i0 * 2];
        f32x4 c = *(const f32x4*)&src[i0 * 2 + 4];
        u16x4 t0v = { f2b(a[0]), f2b(a[2]), f2b(c[0]), f2b(c[2]) };
        u16x4 t1v = { f2b(a[1]), f2b(a[3]), f2b(c[1]), f2b(c[3]) };
        *(u16x4*)&W1[(size_t)m * 512 + i0]       = t0v;   // tap 0 block
        *(u16x4*)&W1[(size_t)m * 512 + 256 + i0] = t1v;   // tap 1 block
    } else {                                  // W2: 512 rows x 64 threads
        int g2 = g - 512 * 64;
        int m = g2 >> 6, i0 = (g2 & 63) * 4;
        const float* src = (m < 256) ? wr + ((size_t)m << 8)
                                     : wsk + ((size_t)(m - 256) << 8);
        f32x4 a = *(const f32x4*)&src[i0];
        u16x4 o = { f2b(a[0]), f2b(a[1]), f2b(a[2]), f2b(a[3]) };
        *(u16x4*)&W2[(size_t)m * 256 + i0] = o;
    }
}

// 512 threads = 8 waves, 2 waves/SIMD (256-reg budget for deep prefetch).
// Wave w owns output channels [w*32, w*32+32) (filter+gate pair rows).
// Each wave covers ALL 128 tokens (tm=0..7) -> W fragment reuse 8x per load.
// MFMA roles: A = x-fragment (M=16 tokens), B = W-fragment (N=16 out-ch)
// => D: row = quad*4+r = token, col = lane&15 = channel.
__global__ __launch_bounds__(512, 2)
void fused_block(const float* __restrict__ x,
                 const ushort* __restrict__ W1, const ushort* __restrict__ W2,
                 const float* __restrict__ b_filt, const float* __restrict__ b_gate,
                 const float* __restrict__ b_res,  const float* __restrict__ b_skip,
                 float* __restrict__ out) {
    // rows 0..135: x[token][channel] bf16 swizzled (token = t0-8+row);
    // after GEMM1, rows 0..127 are reused for z[token][channel].
    __shared__ __align__(16) char lds[XROWS * ROWB];   // 69632 B

    const int tid = threadIdx.x;
    const int b  = blockIdx.x >> 5;           // 32 tiles per batch
    const int t0 = (blockIdx.x & 31) * NT;
    const float* X = x + (size_t)b * CH * TT;
    const int tg0 = t0 - HALO;

    // ---------------- stage x (f32 -> bf16, transposed, swizzled) ----------------
    {
        const int tc4 = tid & 3;          // token sub-chunk (4 tokens)
        const int cp  = tid >> 2;         // channel pair 0..127
        const int c0  = cp * 2;
        const float* Xa = X + (size_t)c0 * TT;
        const float* Xb = Xa + TT;
        #pragma unroll
        for (int it = 0; it < 8; ++it) {  // rows 0..127
            int tg = tg0 + it * 16 + tc4 * 4;
            f32x4 va = (f32x4){0.f,0.f,0.f,0.f}, vb = va;
            if (tg >= 0) { va = *(const f32x4*)&Xa[tg]; vb = *(const f32x4*)&Xb[tg]; }
            #pragma unroll
            for (int e = 0; e < 4; ++e) {
                int row = it * 16 + tc4 * 4 + e;
                unsigned pk = (unsigned)f2b(va[e]) | ((unsigned)f2b(vb[e]) << 16);
                *(unsigned*)(lds + swz(row, cp * 4)) = pk;
            }
        }
        // tail rows 128..135 = tokens t0+120..t0+127 (always in range)
        int c = tid & 255, half = tid >> 8;
        f32x4 v = *(const f32x4*)&X[(size_t)c * TT + tg0 + 128 + half * 4];
        #pragma unroll
        for (int e = 0; e < 4; ++e) {
            int row = 128 + half * 4 + e;
            *(ushort*)(lds + swz(row, c * 2)) = f2b(v[e]);
        }
    }
    __syncthreads();

    const int wv = tid >> 6, lane = tid & 63;
    const int l16 = lane & 15, quad = lane >> 4;
    // B-operand rows: cn 0/1 = filter ch, cn 2/3 = gate ch (paired with 0/1)
    int mrow[4];
    mrow[0] = wv * 32 + l16;        mrow[1] = wv * 32 + 16 + l16;
    mrow[2] = 256 + mrow[0];        mrow[3] = 256 + mrow[1];
    const ushort* W1p[4];
    const ushort* W2p[4];
    #pragma unroll
    for (int cn = 0; cn < 4; ++cn) {
        W1p[cn] = W1 + (size_t)mrow[cn] * 512 + quad * 8;
        W2p[cn] = W2 + (size_t)mrow[cn] * 256 + quad * 8;
    }

    // ---------------- GEMM1: acc[token-tile][ch-tile] over K=512 ----------------
    f32x4 acc[8][4];
    #pragma unroll
    for (int i = 0; i < 8; ++i)
        #pragma unroll
        for (int j = 0; j < 4; ++j) acc[i][j] = (f32x4){0.f,0.f,0.f,0.f};

    s16x8 wc[4], wn[4];
    #pragma unroll
    for (int cn = 0; cn < 4; ++cn) wc[cn] = *(const s16x8*)&W1p[cn][0];

    #pragma unroll
    for (int kq = 0; kq < 16; ++kq) {
        // prefetch next kq's W fragments (L2) while current MFMAs run
        #pragma unroll
        for (int cn = 0; cn < 4; ++cn)
            wn[cn] = (kq < 15) ? *(const s16x8*)&W1p[cn][(kq + 1) * 32] : wc[cn];
        const int tap = kq >> 3, ci = kq & 7;
        s16x8 xf[8];
        #pragma unroll
        for (int tm = 0; tm < 8; ++tm)
            xf[tm] = *(const s16x8*)(lds + swz(tm * 16 + l16 + 8 * tap,
                                              ci * 64 + quad * 16));
        #pragma unroll
        for (int cn = 0; cn < 4; ++cn)
            #pragma unroll
            for (int tm = 0; tm < 8; ++tm)
                acc[tm][cn] = __builtin_amdgcn_mfma_f32_16x16x32_bf16(xf[tm], wc[cn], acc[tm][cn], 0, 0, 0);
        #pragma unroll
        for (int cn = 0; cn < 4; ++cn) wc[cn] = wn[cn];
    }

    // prefetch GEMM2's first W fragments; latency hides under activations
    s16x8 wc2[4], wn2[4];
    #pragma unroll
    for (int cn = 0; cn < 4; ++cn) wc2[cn] = *(const s16x8*)&W2p[cn][0];

    __syncthreads();   // all GEMM1 LDS reads done before z overwrites rows 0..127

    // ---------------- activations -> z (bf16) rows 0..127 ----------------
    #pragma unroll
    for (int cn = 0; cn < 2; ++cn) {
        const int zc = wv * 32 + cn * 16 + l16;
        const float bfv = b_filt[zc], bgv = b_gate[zc];
        #pragma unroll
        for (int tm = 0; tm < 8; ++tm) {
            #pragma unroll
            for (int r = 0; r < 4; ++r) {
                float fv = acc[tm][cn][r]     + bfv;
                float gv = acc[tm][cn + 2][r] + bgv;
                int row = tm * 16 + quad * 4 + r;
                *(ushort*)(lds + swz(row, zc * 2)) = f2b(fast_tanh(fv) * fast_sigmoid(gv));
            }
        }
    }
    __syncthreads();

    // ---------------- GEMM2 over K=256 (reuse acc registers) ----------------
    #pragma unroll
    for (int i = 0; i < 8; ++i)
        #pragma unroll
        for (int j = 0; j < 4; ++j) acc[i][j] = (f32x4){0.f,0.f,0.f,0.f};

    #pragma unroll
    for (int kq = 0; kq < 8; ++kq) {
        #pragma unroll
        for (int cn = 0; cn < 4; ++cn)
            wn2[cn] = (kq < 7) ? *(const s16x8*)&W2p[cn][(kq + 1) * 32] : wc2[cn];
        s16x8 zf[8];
        #pragma unroll
        for (int tm = 0; tm < 8; ++tm)
            zf[tm] = *(const s16x8*)(lds + swz(tm * 16 + l16, kq * 64 + quad * 16));
        #pragma unroll
        for (int cn = 0; cn < 4; ++cn)
            #pragma unroll
            for (int tm = 0; tm < 8; ++tm)
                acc[tm][cn] = __builtin_amdgcn_mfma_f32_16x16x32_bf16(zf[tm], wc2[cn], acc[tm][cn], 0, 0, 0);
        #pragma unroll
        for (int cn = 0; cn < 4; ++cn) wc2[cn] = wn2[cn];
    }

    // ---------------- epilogue: vectorized f32x4 stores ----------------
    const size_t OUT1 = (size_t)NB * CH * TT;
    #pragma unroll
    for (int cn = 0; cn < 2; ++cn) {
        const int ch = wv * 32 + cn * 16 + l16;
        const float br = b_res[ch], bs = b_skip[ch];
        const float* Xc = X + (size_t)ch * TT + t0;
        float* O0 = out + ((size_t)(b * CH + ch)) * TT + t0;
        float* O1 = O0 + OUT1;
        #pragma unroll
        for (int tm = 0; tm < 8; ++tm) {
            const int ttk = tm * 16 + quad * 4;
            f32x4 xv = *(const f32x4*)&Xc[ttk];       // exact f32 x (L2-hot)
            f32x4 o0, o1;
            #pragma unroll
            for (int r = 0; r < 4; ++r) {
                o0[r] = xv[r] + acc[tm][cn][r] + br;
                o1[r] = acc[tm][cn + 2][r] + bs;
            }
            *(f32x4*)&O0[ttk] = o0;
            *(f32x4*)&O1[ttk] = o1;
        }
    }
}

extern "C" void kernel_launch(void* const* d_in, const int* in_sizes, int n_in,
                              void* d_out, int out_size, void* d_ws, size_t ws_size,
                              hipStream_t stream) {
    const float* x   = (const float*)d_in[0];
    const float* wf  = (const float*)d_in[1];
    const float* bfi = (const float*)d_in[2];
    const float* wg  = (const float*)d_in[3];
    const float* bg  = (const float*)d_in[4];
    const float* wr  = (const float*)d_in[5];
    const float* br  = (const float*)d_in[6];
    const float* wsk = (const float*)d_in[7];
    const float* bs  = (const float*)d_in[8];

    ushort* W1 = (ushort*)d_ws;                  // 512*512 bf16
    ushort* W2 = W1 + 512 * 512;                 // 512*256 bf16

    prep_w<<<128, 512, 0, stream>>>(wf, wg, wr, wsk, W1, W2);

    const int nBlocks = NB * (TT / NT);          // 512
    fused_block<<<nBlocks, 512, 0, stream>>>(x, W1, W2, bfi, bg, br, bs,
                                             (float*)d_out);
}